// Round 4
// baseline (142.620 us; speedup 1.0000x reference)
//
#include <hip/hip_runtime.h>
#include <cstddef>

#define N_TOT   8
#define R_TOT   2048
#define KK      16
#define CL      64
#define CM      128
#define EPSV    1e-5f
#define CNTF    262144.0f

typedef float    f32x4  __attribute__((ext_vector_type(4)));
typedef short    bf16x8 __attribute__((ext_vector_type(8)));
typedef unsigned u32x4  __attribute__((ext_vector_type(4)));

union FragU { bf16x8 f; unsigned u[4]; };

// Pre-packed weights (written by stats block 0) + final BN scale/shift
// (written by the LAST stats block via counter handshake). Device globals:
// zero-init at load, deterministic, rewritten/reset every launch.
__device__ float    g_w1f[72*4];      // float4 rows {w1_0,w1_1,w1_2,b1} per channel,
                                      // 8-row groups padded to stride 9 (bank spread)
__device__ unsigned g_w2p[8*64*4];    // packed bf16 B-frags for lift2
__device__ float    g_bn[8];          // {sc0,sc1,sc2,sh0,sh1,sh2,0,0}
__device__ unsigned g_cnt = 0;        // stats completion counter (self-resetting)

__device__ __forceinline__ float elu_f(float x){
    return x > 0.f ? x : (__expf(x) - 1.f);
}

#if defined(__has_builtin) && __has_builtin(__builtin_amdgcn_cvt_pk_bf16_f32)
__device__ __forceinline__ unsigned pk_bf16(float a, float b){
    auto v = __builtin_amdgcn_cvt_pk_bf16_f32(a, b);   // lo=a, hi=b
    unsigned u; __builtin_memcpy(&u, &v, 4);
    return u;
}
#else
__device__ __forceinline__ unsigned pk_bf16(float a, float b){
    unsigned ua = __float_as_uint(a), ub = __float_as_uint(b);
    ua += 0x7fff + ((ua >> 16) & 1);
    ub += 0x7fff + ((ub >> 16) & 1);
    return (ua >> 16) | (ub & 0xffff0000u);
}
#endif
__device__ __forceinline__ float bf_lo(unsigned u){ return __uint_as_float(u << 16); }
__device__ __forceinline__ float bf_hi(unsigned u){ return __uint_as_float(u & 0xffff0000u); }

__device__ __forceinline__ void split4(const float* x, unsigned* o){
    unsigned h01 = pk_bf16(x[0], x[1]);
    unsigned h23 = pk_bf16(x[2], x[3]);
    float l0 = x[0] - bf_lo(h01), l1 = x[1] - bf_hi(h01);
    float l2 = x[2] - bf_lo(h23), l3 = x[3] - bf_hi(h23);
    o[0] = h01; o[1] = h23; o[2] = pk_bf16(l0, l1); o[3] = pk_bf16(l2, l3);
}

// ---------------- Pass 1: BN partials + weight pre-pack + last-block BN finish ----
// R10: the former 1-block xconv_bn kernel was ~100% launch overhead; fold its
// reduce into the last-finishing stats block (store partials -> threadfence ->
// atomic counter -> last block reduces). Saves one dispatch + one launch gap.
__global__ __launch_bounds__(256) void xconv_stats(
    const float* __restrict__ p, const float* __restrict__ P,
    const float* __restrict__ w1, const float* __restrict__ b1,
    const float* __restrict__ w2,
    const float* __restrict__ gamma, const float* __restrict__ beta,
    float* __restrict__ ws)
{
    const int tid = threadIdx.x;
    const int g = blockIdx.x*256 + tid;                // group of 4 neighbor rows
    const float4* P4 = (const float4*)(P + (size_t)g*12);
    float4 a = P4[0], b = P4[1], c = P4[2];
    const int nr = g >> 2;
    float pp0 = p[nr*3], pp1 = p[nr*3+1], pp2 = p[nr*3+2];
    float vx0=a.x-pp0, vx1=a.w-pp0, vx2=b.z-pp0, vx3=c.y-pp0;
    float vy0=a.y-pp1, vy1=b.x-pp1, vy2=b.w-pp1, vy3=c.z-pp1;
    float vz0=a.z-pp2, vz1=b.y-pp2, vz2=c.x-pp2, vz3=c.w-pp2;
    float s1[3], s2[3];
    s1[0]=vx0+vx1+vx2+vx3; s2[0]=vx0*vx0+vx1*vx1+vx2*vx2+vx3*vx3;
    s1[1]=vy0+vy1+vy2+vy3; s2[1]=vy0*vy0+vy1*vy1+vy2*vy2+vy3*vy3;
    s1[2]=vz0+vz1+vz2+vz3; s2[2]=vz0*vz0+vz1*vz1+vz2*vz2+vz3*vz3;

    #pragma unroll
    for (int off = 32; off > 0; off >>= 1){
        #pragma unroll
        for (int d = 0; d < 3; d++){
            s1[d] += __shfl_down(s1[d], off, 64);
            s2[d] += __shfl_down(s2[d], off, 64);
        }
    }
    __shared__ float red[4][6];
    __shared__ int   sLast;
    int wave = tid >> 6, lane = tid & 63;
    if (lane == 0){
        #pragma unroll
        for (int d = 0; d < 3; d++){ red[wave][d] = s1[d]; red[wave][3+d] = s2[d]; }
    }
    __syncthreads();
    if (tid < 8){
        float v = 0.f;
        if (tid < 6) v = red[0][tid] + red[1][tid] + red[2][tid] + red[3][tid];
        ws[blockIdx.x*8 + tid] = v;            // slots 6,7 = 0 (defined)
        __threadfence();                        // release partials (device scope)
    }

    // ---- weight pre-pack (block 0 only) ----
    if (blockIdx.x == 0){
        if (wave == 0){
            f32x4 w4 = { w1[lane], w1[64+lane], w1[128+lane], b1[lane] };
            *(f32x4*)&g_w1f[((lane>>3)*9 + (lane&7))*4] = w4;
        } else if (wave == 1){
            const int lo16 = lane & 15, quad = lane >> 4;
            #pragma unroll
            for (int bb = 0; bb < 4; bb++)
                #pragma unroll
                for (int s = 0; s < 2; s++){
                    u32x4 f;
                    #pragma unroll
                    for (int d = 0; d < 4; d++){
                        int q0 = s*32 + quad*8 + d*2;
                        int idx = q0*64 + bb*16 + lo16;
                        f[d] = pk_bf16(w2[idx], w2[idx + 64]);
                    }
                    *(u32x4*)&g_w2p[((bb*2 + s)*64 + lane)*4] = f;
                }
        }
    }

    // ---- last-block BN finish ----
    __syncthreads();
    if (tid == 0){
        unsigned old = atomicAdd(&g_cnt, 1u);
        sLast = (old == 255u);
        if (sLast) atomicExch(&g_cnt, 0u);     // reset for next launch/replay
    }
    __syncthreads();
    if (sLast && tid < 64){
        __threadfence();                        // acquire all blocks' partials
        float t1[3] = {0.f,0.f,0.f}, t2[3] = {0.f,0.f,0.f};
        const f32x4* wp = (const f32x4*)ws;
        #pragma unroll
        for (int i = 0; i < 4; i++){
            int row = tid + i*64;
            f32x4 pa = wp[row*2], pb = wp[row*2 + 1];
            t1[0] += pa.x; t1[1] += pa.y; t1[2] += pa.z;
            t2[0] += pa.w; t2[1] += pb.x; t2[2] += pb.y;
        }
        #pragma unroll
        for (int off = 32; off > 0; off >>= 1){
            #pragma unroll
            for (int d = 0; d < 3; d++){
                t1[d] += __shfl_xor(t1[d], off, 64);
                t2[d] += __shfl_xor(t2[d], off, 64);
            }
        }
        if (tid == 0){
            #pragma unroll
            for (int d = 0; d < 3; d++){
                float mean = t1[d] * (1.0f/CNTF);
                float var  = t2[d] * (1.0f/CNTF) - mean*mean;
                float s    = gamma[d] * rsqrtf(var + EPSV);
                g_bn[d] = s; g_bn[3+d] = beta[d] - mean*s;
            }
            g_bn[6] = 0.f; g_bn[7] = 0.f;
        }
    }
}

// ---------------- Pass 2: fused MFMA kernel ----------------
// 4096 blocks x 256 thr, one point per wave, __launch_bounds__(256,5) ->
// 5 waves/SIMD (R9 lever, confirmed: 148.7 -> 139.5). R10: F read as 4x
// global_load_dwordx4 instead of 16x dword via channel-regroup — tile g owns
// channels c = 4*lo16 + g; sEndw rows for c>=64 permuted to keep the stride-20
// (2-way-free) bank pattern; 4-shuffle epilogue redistributes to writing lane.
__global__ __launch_bounds__(256, 5) void xconv_main(
    const float* __restrict__ p,   const float* __restrict__ P,
    const float* __restrict__ F,
    const float* __restrict__ mlpw,const float* __restrict__ mlpb,
    const float* __restrict__ midw,const float* __restrict__ midb,
    const float* __restrict__ b2,
    const float* __restrict__ endw,const float* __restrict__ endb,
    float* __restrict__ out)
{
    __shared__ float    sEndw[128*20];     // 10240 B, rows padded to 80 B
    __shared__ float    sW1f[72*4];        //  1152 B, {w1_0,w1_1,w1_2,b1} per channel
    __shared__ unsigned sW2[8*64*4];       //  8192 B, per-(b,s,lane) 16 B frags
    __shared__ float    sMid[16*4];        //   256 B, {mw0,mw1,mw2,mb} per out col

    const int tid  = threadIdx.x;
    const int lane = tid & 63;
    const int lo16 = lane & 15;
    const int quad = lane >> 4;
    const int wave = tid >> 6;

    // ---- parallel LDS staging (vector copies of pre-packed weights) ----
    if (wave == 0){
        *(f32x4*)&sW1f[lane*4] = *(const f32x4*)&g_w1f[lane*4];
        if (lane < 8)
            *(f32x4*)&sW1f[(64+lane)*4] = *(const f32x4*)&g_w1f[(64+lane)*4];
    } else if (wave == 1){
        #pragma unroll
        for (int i = 0; i < 8; i++)
            *(u32x4*)&sW2[(i*64+lane)*4] = *(const u32x4*)&g_w2p[(i*64+lane)*4];
    } else {
        int c = tid - 128;                 // 0..127
        // rows 64..127 permuted: channel 64+cf stored at row 64 + (cf&3)*16 + (cf>>2)
        int row = (c < 64) ? c : 64 + ((c-64)&3)*16 + ((c-64)>>2);
        const f32x4* ep = (const f32x4*)endw;
        #pragma unroll
        for (int i = 0; i < 4; i++)
            *(f32x4*)&sEndw[row*20 + i*4] = ep[c*4 + i];
        if (c >= 112){                     // last 16 threads also stage sMid
            int m2 = c - 112;
            f32x4 mv = { midw[m2], midw[16+m2], midw[32+m2], midb[m2] };
            *(f32x4*)&sMid[m2*4] = mv;
        }
    }

    // ---- BN scale/shift: precomputed by stats' last block, 8-float load ----
    f32x4 bn0 = *(const f32x4*)&g_bn[0];
    float sc0 = bn0.x, sc1 = bn0.y, sc2 = bn0.z, sh0 = bn0.w;
    float sh1 = g_bn[4], sh2 = g_bn[5];

    // ---- small persistent regs ----
    FragU mlpA[2];
    {
        float mw[4];
        #pragma unroll
        for (int r = 0; r < 4; r++) mw[r] = mlpw[(quad*4 + r)*16 + lo16];
        unsigned o[4]; split4(mw, o);
        mlpA[0].u[0]=o[0]; mlpA[0].u[1]=o[1]; mlpA[0].u[2]=o[0]; mlpA[0].u[3]=o[1];
        mlpA[1].u[0]=o[2]; mlpA[1].u[1]=o[3]; mlpA[1].u[2]=o[2]; mlpA[1].u[3]=o[3];
    }
    float mlpbr[4];
    #pragma unroll
    for (int r = 0; r < 4; r++) mlpbr[r] = mlpb[quad*4 + r];
    float b2r[4];
    #pragma unroll
    for (int b = 0; b < 4; b++) b2r[b] = b2[b*16 + lo16];
    const float endb0 = endb[lane], endb1 = endb[64 + lane];

    __syncthreads();

    const int nr = blockIdx.x*4 + wave;    // 0..16383, one point per wave

    // ---- P/p first (needed immediately), then F as 4 dwordx4 (needed last) ----
    const int pb = nr*48 + lo16*3;
    float P0 = P[pb], P1 = P[pb+1], P2 = P[pb+2];
    float pp0 = p[nr*3], pp1 = p[nr*3+1], pp2 = p[nr*3+2];

    const float4* fp = (const float4*)(F + (size_t)nr*1024 + (size_t)(quad*4)*64);
    float4 q0 = fp[lo16], q1 = fp[16+lo16], q2 = fp[32+lo16], q3 = fp[48+lo16];
    unsigned fh01[4] = { pk_bf16(q0.x,q1.x), pk_bf16(q0.y,q1.y),
                         pk_bf16(q0.z,q1.z), pk_bf16(q0.w,q1.w) };
    unsigned fh23[4] = { pk_bf16(q2.x,q3.x), pk_bf16(q2.y,q3.y),
                         pk_bf16(q2.z,q3.z), pk_bf16(q2.w,q3.w) };

    const float pn0 = (P0 - pp0)*sc0 + sh0;
    const float pn1 = (P1 - pp1)*sc1 + sh1;
    const float pn2 = (P2 - pp2)*sc2 + sh2;

    // ---- h1 = elu(Pn @ w1 + b1): fp32 weights, broadcast LDS reads ----
    FragU hf[2];
    #pragma unroll
    for (int s = 0; s < 2; s++){
        const f32x4* wp = (const f32x4*)&sW1f[((s*4 + quad)*9)*4];
        #pragma unroll
        for (int d = 0; d < 4; d++){
            f32x4 wa = wp[2*d], wb = wp[2*d+1];
            float h0  = fmaf(pn2, wa.z, fmaf(pn1, wa.y, fmaf(pn0, wa.x, wa.w)));
            float h1v = fmaf(pn2, wb.z, fmaf(pn1, wb.y, fmaf(pn0, wb.x, wb.w)));
            hf[s].u[d] = pk_bf16(elu_f(h0), elu_f(h1v));
        }
    }

    // ---- X0 (exact fp32) -> split B-frag ----
    float x0[4];
    #pragma unroll
    for (int j = 0; j < 4; j++){
        f32x4 mw = *(const f32x4*)&sMid[(quad*4 + j)*4];
        x0[j] = fmaf(pn2, mw.z, fmaf(pn1, mw.y, fmaf(pn0, mw.x, mw.w)));
    }
    FragU x0f; split4(x0, x0f.u);

    // ---- mlp: X^T = mlpw^T @ X0^T (exact), ELU, split -> agg A-frag ----
    f32x4 dx = {0.f,0.f,0.f,0.f};
    dx = __builtin_amdgcn_mfma_f32_16x16x32_bf16(mlpA[0].f, x0f.f, dx, 0,0,0);
    dx = __builtin_amdgcn_mfma_f32_16x16x32_bf16(mlpA[1].f, x0f.f, dx, 0,0,0);
    float xv[4];
    #pragma unroll
    for (int r = 0; r < 4; r++) xv[r] = elu_f(dx[r] + mlpbr[r]);
    FragU xA; split4(xv, xA.u);

    float o0 = 0.f;

    // ---- tiles 0..3: lift2 (MFMA) -> ELU -> hi-dup B-frag -> agg ----
    #pragma unroll
    for (int b = 0; b < 4; b++){
        FragU wf0, wf1;
        *(u32x4*)wf0.u = *(const u32x4*)&sW2[((b*2 + 0)*64 + lane)*4];
        *(u32x4*)wf1.u = *(const u32x4*)&sW2[((b*2 + 1)*64 + lane)*4];
        f32x4 dl = {0.f,0.f,0.f,0.f};
        dl = __builtin_amdgcn_mfma_f32_16x16x32_bf16(hf[0].f, wf0.f, dl, 0,0,0);
        dl = __builtin_amdgcn_mfma_f32_16x16x32_bf16(hf[1].f, wf1.f, dl, 0,0,0);
        float fl[4];
        #pragma unroll
        for (int r = 0; r < 4; r++) fl[r] = elu_f(dl[r] + b2r[b]);
        FragU bfg;
        unsigned h01 = pk_bf16(fl[0], fl[1]), h23 = pk_bf16(fl[2], fl[3]);
        bfg.u[0] = h01; bfg.u[1] = h23; bfg.u[2] = h01; bfg.u[3] = h23;
        f32x4 da = {0.f,0.f,0.f,0.f};
        da = __builtin_amdgcn_mfma_f32_16x16x32_bf16(xA.f, bfg.f, da, 0,0,0);
        const float4 ew = *(const float4*)&sEndw[(b*16 + lo16)*20 + quad*4];
        float pt = da[0]*ew.x + da[1]*ew.y + da[2]*ew.z + da[3]*ew.w;
        pt += __shfl_xor(pt, 16, 64);
        pt += __shfl_xor(pt, 32, 64);
        if (b == quad) o0 = pt;            // c = b*16+lo16 == lane
    }
    // ---- tiles 4..7: F channels c = 4*lo16 + g (regrouped for dwordx4 loads) ----
    float pt4[4];
    #pragma unroll
    for (int g = 0; g < 4; g++){
        FragU bfg;
        bfg.u[0] = fh01[g]; bfg.u[1] = fh23[g];
        bfg.u[2] = fh01[g]; bfg.u[3] = fh23[g];
        f32x4 da = {0.f,0.f,0.f,0.f};
        da = __builtin_amdgcn_mfma_f32_16x16x32_bf16(xA.f, bfg.f, da, 0,0,0);
        const float4 ew = *(const float4*)&sEndw[(64 + g*16 + lo16)*20 + quad*4];
        float pt = da[0]*ew.x + da[1]*ew.y + da[2]*ew.z + da[3]*ew.w;
        pt += __shfl_xor(pt, 16, 64);
        pt += __shfl_xor(pt, 32, 64);
        pt4[g] = pt;                       // value for channel 64 + 4*lo16 + g
    }
    // redistribute: lane L needs channel 64+L -> tile g=L&3 from lane 20*quad+(lo16>>2)
    const int src = quad*20 + (lo16 >> 2);
    float t0 = __shfl(pt4[0], src, 64), t1 = __shfl(pt4[1], src, 64);
    float t2 = __shfl(pt4[2], src, 64), t3 = __shfl(pt4[3], src, 64);
    float ta = (lo16 & 1) ? t1 : t0;
    float tb = (lo16 & 1) ? t3 : t2;
    float o1 = (lo16 & 2) ? tb : ta;

    out[(size_t)nr*CM + lane]      = o0 + endb0;
    out[(size_t)nr*CM + 64 + lane] = o1 + endb1;
}

extern "C" void kernel_launch(void* const* d_in, const int* in_sizes, int n_in,
                              void* d_out, int out_size, void* d_ws, size_t ws_size,
                              hipStream_t stream)
{
    const float* p     = (const float*)d_in[0];
    const float* P     = (const float*)d_in[1];
    const float* F     = (const float*)d_in[2];
    const float* gamma = (const float*)d_in[3];
    const float* beta  = (const float*)d_in[4];
    const float* w1    = (const float*)d_in[5];
    const float* b1    = (const float*)d_in[6];
    const float* w2    = (const float*)d_in[7];
    const float* b2    = (const float*)d_in[8];
    const float* midw  = (const float*)d_in[9];
    const float* midb  = (const float*)d_in[10];
    const float* mlpw  = (const float*)d_in[11];
    const float* mlpb  = (const float*)d_in[12];
    const float* endw  = (const float*)d_in[13];
    const float* endb  = (const float*)d_in[14];
    float* ws  = (float*)d_ws;
    float* out = (float*)d_out;

    xconv_stats<<<256, 256, 0, stream>>>(p, P, w1, b1, w2, gamma, beta, ws);
    xconv_main <<<4096, 256, 0, stream>>>(p, P, F, mlpw, mlpb, midw, midb,
                                          b2, endw, endb, out);
}

// Round 5
// 138.807 us; speedup vs baseline: 1.0275x; 1.0275x over previous
//
#include <hip/hip_runtime.h>
#include <cstddef>

#define N_TOT   8
#define R_TOT   2048
#define KK      16
#define CL      64
#define CM      128
#define EPSV    1e-5f
#define CNTF    262144.0f

typedef float    f32x4  __attribute__((ext_vector_type(4)));
typedef short    bf16x8 __attribute__((ext_vector_type(8)));
typedef unsigned u32x4  __attribute__((ext_vector_type(4)));

union FragU { bf16x8 f; unsigned u[4]; };

// Pre-packed weights (written by stats block 0) + final BN scale/shift
// (written by xconv_bn). Device globals: deterministic, rewritten each launch.
__device__ float    g_w1f[72*4];      // float4 rows {w1_0,w1_1,w1_2,b1} per channel,
                                      // 8-row groups padded to stride 9 (bank spread)
__device__ unsigned g_w2p[8*64*4];    // packed bf16 B-frags for lift2
__device__ float    g_bn[8];          // {sc0,sc1,sc2,sh0,sh1,sh2,0,0}

__device__ __forceinline__ float elu_f(float x){
    return x > 0.f ? x : (__expf(x) - 1.f);
}

#if defined(__has_builtin) && __has_builtin(__builtin_amdgcn_cvt_pk_bf16_f32)
__device__ __forceinline__ unsigned pk_bf16(float a, float b){
    auto v = __builtin_amdgcn_cvt_pk_bf16_f32(a, b);   // lo=a, hi=b
    unsigned u; __builtin_memcpy(&u, &v, 4);
    return u;
}
#else
__device__ __forceinline__ unsigned pk_bf16(float a, float b){
    unsigned ua = __float_as_uint(a), ub = __float_as_uint(b);
    ua += 0x7fff + ((ua >> 16) & 1);
    ub += 0x7fff + ((ub >> 16) & 1);
    return (ua >> 16) | (ub & 0xffff0000u);
}
#endif
__device__ __forceinline__ float bf_lo(unsigned u){ return __uint_as_float(u << 16); }
__device__ __forceinline__ float bf_hi(unsigned u){ return __uint_as_float(u & 0xffff0000u); }

__device__ __forceinline__ void split4(const float* x, unsigned* o){
    unsigned h01 = pk_bf16(x[0], x[1]);
    unsigned h23 = pk_bf16(x[2], x[3]);
    float l0 = x[0] - bf_lo(h01), l1 = x[1] - bf_hi(h01);
    float l2 = x[2] - bf_lo(h23), l3 = x[3] - bf_hi(h23);
    o[0] = h01; o[1] = h23; o[2] = pk_bf16(l0, l1); o[3] = pk_bf16(l2, l3);
}

// ---------------- Pass 1: per-block BN partials + weight pre-pack ----------------
__global__ __launch_bounds__(256) void xconv_stats(
    const float* __restrict__ p, const float* __restrict__ P,
    const float* __restrict__ w1, const float* __restrict__ b1,
    const float* __restrict__ w2, float* __restrict__ ws)
{
    const int tid = threadIdx.x;
    const int g = blockIdx.x*256 + tid;                // group of 4 neighbor rows
    const float4* P4 = (const float4*)(P + (size_t)g*12);
    float4 a = P4[0], b = P4[1], c = P4[2];
    const int nr = g >> 2;
    float pp0 = p[nr*3], pp1 = p[nr*3+1], pp2 = p[nr*3+2];
    float vx0=a.x-pp0, vx1=a.w-pp0, vx2=b.z-pp0, vx3=c.y-pp0;
    float vy0=a.y-pp1, vy1=b.x-pp1, vy2=b.w-pp1, vy3=c.z-pp1;
    float vz0=a.z-pp2, vz1=b.y-pp2, vz2=c.x-pp2, vz3=c.w-pp2;
    float s1[3], s2[3];
    s1[0]=vx0+vx1+vx2+vx3; s2[0]=vx0*vx0+vx1*vx1+vx2*vx2+vx3*vx3;
    s1[1]=vy0+vy1+vy2+vy3; s2[1]=vy0*vy0+vy1*vy1+vy2*vy2+vy3*vy3;
    s1[2]=vz0+vz1+vz2+vz3; s2[2]=vz0*vz0+vz1*vz1+vz2*vz2+vz3*vz3;

    #pragma unroll
    for (int off = 32; off > 0; off >>= 1){
        #pragma unroll
        for (int d = 0; d < 3; d++){
            s1[d] += __shfl_down(s1[d], off, 64);
            s2[d] += __shfl_down(s2[d], off, 64);
        }
    }
    __shared__ float red[4][6];
    int wave = tid >> 6, lane = tid & 63;
    if (lane == 0){
        #pragma unroll
        for (int d = 0; d < 3; d++){ red[wave][d] = s1[d]; red[wave][3+d] = s2[d]; }
    }
    __syncthreads();
    float v = 0.f;
    if (tid < 6) v = red[0][tid] + red[1][tid] + red[2][tid] + red[3][tid];
    if (tid < 8) ws[blockIdx.x*8 + tid] = v;           // slots 6,7 = 0 (defined)

    // ---- weight pre-pack (block 0 only) ----
    if (blockIdx.x == 0){
        if (wave == 0){
            f32x4 w4 = { w1[lane], w1[64+lane], w1[128+lane], b1[lane] };
            *(f32x4*)&g_w1f[((lane>>3)*9 + (lane&7))*4] = w4;
        } else if (wave == 1){
            const int lo16 = lane & 15, quad = lane >> 4;
            #pragma unroll
            for (int bb = 0; bb < 4; bb++)
                #pragma unroll
                for (int s = 0; s < 2; s++){
                    u32x4 f;
                    #pragma unroll
                    for (int d = 0; d < 4; d++){
                        int q0 = s*32 + quad*8 + d*2;
                        int idx = q0*64 + bb*16 + lo16;
                        f[d] = pk_bf16(w2[idx], w2[idx + 64]);
                    }
                    *(u32x4*)&g_w2p[((bb*2 + s)*64 + lane)*4] = f;
                }
        }
    }
}

// ---------------- Pass 1b: reduce BN partials -> sc/sh (1 block, 64 thr) ----------------
// R10 tried folding this into stats (last-block counter pattern) bundled with an
// F-load regroup: composite regressed +3.1us, unattributable -> reverted both.
__global__ __launch_bounds__(64) void xconv_bn(
    const float* __restrict__ ws,
    const float* __restrict__ gamma, const float* __restrict__ beta)
{
    const int lane = threadIdx.x;
    float s1[3] = {0.f,0.f,0.f}, s2[3] = {0.f,0.f,0.f};
    const f32x4* wp = (const f32x4*)ws;
    #pragma unroll
    for (int i = 0; i < 4; i++){
        int row = lane + i*64;
        f32x4 pa = wp[row*2], pb = wp[row*2 + 1];
        s1[0] += pa.x; s1[1] += pa.y; s1[2] += pa.z;
        s2[0] += pa.w; s2[1] += pb.x; s2[2] += pb.y;
    }
    #pragma unroll
    for (int off = 32; off > 0; off >>= 1){
        #pragma unroll
        for (int d = 0; d < 3; d++){
            s1[d] += __shfl_xor(s1[d], off, 64);
            s2[d] += __shfl_xor(s2[d], off, 64);
        }
    }
    if (lane == 0){
        #pragma unroll
        for (int d = 0; d < 3; d++){
            float mean = s1[d] * (1.0f/CNTF);
            float var  = s2[d] * (1.0f/CNTF) - mean*mean;
            float s    = gamma[d] * rsqrtf(var + EPSV);
            g_bn[d] = s; g_bn[3+d] = beta[d] - mean*s;
        }
        g_bn[6] = 0.f; g_bn[7] = 0.f;
    }
}

// ---------------- Pass 2: fused MFMA kernel ----------------
// 4096 blocks x 256 thr, one point per wave. Latency-bound regime (R8 counters:
// no pipe >45%); occupancy ladder: 124 VGPR/4 waves = 41us (R8), cap 102/5 waves
// = ~30us (R9, total 148.7->139.5). R11: cap 85 -> 6 waves/SIMD (+20% TLP);
// LDS (6x19.9KB=117KB) and threads (1536) leave VGPR as the only binding limit.
__global__ __launch_bounds__(256, 6) void xconv_main(
    const float* __restrict__ p,   const float* __restrict__ P,
    const float* __restrict__ F,
    const float* __restrict__ mlpw,const float* __restrict__ mlpb,
    const float* __restrict__ midw,const float* __restrict__ midb,
    const float* __restrict__ b2,
    const float* __restrict__ endw,const float* __restrict__ endb,
    float* __restrict__ out)
{
    __shared__ float    sEndw[128*20];     // 10240 B, rows padded to 80 B
    __shared__ float    sW1f[72*4];        //  1152 B, {w1_0,w1_1,w1_2,b1} per channel
    __shared__ unsigned sW2[8*64*4];       //  8192 B, per-(b,s,lane) 16 B frags
    __shared__ float    sMid[16*4];        //   256 B, {mw0,mw1,mw2,mb} per out col

    const int tid  = threadIdx.x;
    const int lane = tid & 63;
    const int lo16 = lane & 15;
    const int quad = lane >> 4;
    const int wave = tid >> 6;

    // ---- parallel LDS staging (vector copies of pre-packed weights) ----
    if (wave == 0){
        *(f32x4*)&sW1f[lane*4] = *(const f32x4*)&g_w1f[lane*4];
        if (lane < 8)
            *(f32x4*)&sW1f[(64+lane)*4] = *(const f32x4*)&g_w1f[(64+lane)*4];
    } else if (wave == 1){
        #pragma unroll
        for (int i = 0; i < 8; i++)
            *(u32x4*)&sW2[(i*64+lane)*4] = *(const u32x4*)&g_w2p[(i*64+lane)*4];
    } else {
        int c = tid - 128;                 // 0..127
        const f32x4* ep = (const f32x4*)endw;
        #pragma unroll
        for (int i = 0; i < 4; i++)
            *(f32x4*)&sEndw[c*20 + i*4] = ep[c*4 + i];
        if (c >= 112){                     // last 16 threads also stage sMid
            int m2 = c - 112;
            f32x4 mv = { midw[m2], midw[16+m2], midw[32+m2], midb[m2] };
            *(f32x4*)&sMid[m2*4] = mv;
        }
    }

    // ---- BN scale/shift: precomputed by xconv_bn, 8-float load ----
    f32x4 bn0 = *(const f32x4*)&g_bn[0];
    float sc0 = bn0.x, sc1 = bn0.y, sc2 = bn0.z, sh0 = bn0.w;
    float sh1 = g_bn[4], sh2 = g_bn[5];

    // ---- small persistent regs ----
    FragU mlpA[2];
    {
        float mw[4];
        #pragma unroll
        for (int r = 0; r < 4; r++) mw[r] = mlpw[(quad*4 + r)*16 + lo16];
        unsigned o[4]; split4(mw, o);
        mlpA[0].u[0]=o[0]; mlpA[0].u[1]=o[1]; mlpA[0].u[2]=o[0]; mlpA[0].u[3]=o[1];
        mlpA[1].u[0]=o[2]; mlpA[1].u[1]=o[3]; mlpA[1].u[2]=o[2]; mlpA[1].u[3]=o[3];
    }
    float mlpbr[4];
    #pragma unroll
    for (int r = 0; r < 4; r++) mlpbr[r] = mlpb[quad*4 + r];
    float b2r[4];
    #pragma unroll
    for (int b = 0; b < 4; b++) b2r[b] = b2[b*16 + lo16];
    const float endb0 = endb[lane], endb1 = endb[64 + lane];

    __syncthreads();

    const int nr = blockIdx.x*4 + wave;    // 0..16383, one point per wave

    // ---- P/p first (needed immediately), then F (needed last, max overlap) ----
    const int pb = nr*48 + lo16*3;
    float P0 = P[pb], P1 = P[pb+1], P2 = P[pb+2];
    float pp0 = p[nr*3], pp1 = p[nr*3+1], pp2 = p[nr*3+2];

    unsigned fh01[4], fh23[4];             // F packed to bf16 right at load
    #pragma unroll
    for (int bt = 0; bt < 4; bt++){
        const size_t fb = (size_t)nr*1024 + (size_t)(quad*4)*64 + bt*16 + lo16;
        float f0 = F[fb], f1 = F[fb + 64], f2 = F[fb + 128], f3 = F[fb + 192];
        fh01[bt] = pk_bf16(f0, f1);
        fh23[bt] = pk_bf16(f2, f3);
    }

    const float pn0 = (P0 - pp0)*sc0 + sh0;
    const float pn1 = (P1 - pp1)*sc1 + sh1;
    const float pn2 = (P2 - pp2)*sc2 + sh2;

    // ---- h1 = elu(Pn @ w1 + b1): fp32 weights, broadcast LDS reads ----
    FragU hf[2];
    #pragma unroll
    for (int s = 0; s < 2; s++){
        const f32x4* wp = (const f32x4*)&sW1f[((s*4 + quad)*9)*4];
        #pragma unroll
        for (int d = 0; d < 4; d++){
            f32x4 wa = wp[2*d], wb = wp[2*d+1];
            float h0  = fmaf(pn2, wa.z, fmaf(pn1, wa.y, fmaf(pn0, wa.x, wa.w)));
            float h1v = fmaf(pn2, wb.z, fmaf(pn1, wb.y, fmaf(pn0, wb.x, wb.w)));
            hf[s].u[d] = pk_bf16(elu_f(h0), elu_f(h1v));
        }
    }

    // ---- X0 (exact fp32) -> split B-frag ----
    float x0[4];
    #pragma unroll
    for (int j = 0; j < 4; j++){
        f32x4 mw = *(const f32x4*)&sMid[(quad*4 + j)*4];
        x0[j] = fmaf(pn2, mw.z, fmaf(pn1, mw.y, fmaf(pn0, mw.x, mw.w)));
    }
    FragU x0f; split4(x0, x0f.u);

    // ---- mlp: X^T = mlpw^T @ X0^T (exact), ELU, split -> agg A-frag ----
    f32x4 dx = {0.f,0.f,0.f,0.f};
    dx = __builtin_amdgcn_mfma_f32_16x16x32_bf16(mlpA[0].f, x0f.f, dx, 0,0,0);
    dx = __builtin_amdgcn_mfma_f32_16x16x32_bf16(mlpA[1].f, x0f.f, dx, 0,0,0);
    float xv[4];
    #pragma unroll
    for (int r = 0; r < 4; r++) xv[r] = elu_f(dx[r] + mlpbr[r]);
    FragU xA; split4(xv, xA.u);

    float o0 = 0.f, o1 = 0.f;

    // ---- tiles 0..3: lift2 (MFMA) -> ELU -> hi-dup B-frag -> agg ----
    #pragma unroll
    for (int b = 0; b < 4; b++){
        FragU wf0, wf1;
        *(u32x4*)wf0.u = *(const u32x4*)&sW2[((b*2 + 0)*64 + lane)*4];
        *(u32x4*)wf1.u = *(const u32x4*)&sW2[((b*2 + 1)*64 + lane)*4];
        f32x4 dl = {0.f,0.f,0.f,0.f};
        dl = __builtin_amdgcn_mfma_f32_16x16x32_bf16(hf[0].f, wf0.f, dl, 0,0,0);
        dl = __builtin_amdgcn_mfma_f32_16x16x32_bf16(hf[1].f, wf1.f, dl, 0,0,0);
        float fl[4];
        #pragma unroll
        for (int r = 0; r < 4; r++) fl[r] = elu_f(dl[r] + b2r[b]);
        FragU bfg;
        unsigned h01 = pk_bf16(fl[0], fl[1]), h23 = pk_bf16(fl[2], fl[3]);
        bfg.u[0] = h01; bfg.u[1] = h23; bfg.u[2] = h01; bfg.u[3] = h23;
        f32x4 da = {0.f,0.f,0.f,0.f};
        da = __builtin_amdgcn_mfma_f32_16x16x32_bf16(xA.f, bfg.f, da, 0,0,0);
        const float4 ew = *(const float4*)&sEndw[(b*16 + lo16)*20 + quad*4];
        float pt = da[0]*ew.x + da[1]*ew.y + da[2]*ew.z + da[3]*ew.w;
        pt += __shfl_xor(pt, 16, 64);
        pt += __shfl_xor(pt, 32, 64);
        if (b == quad) o0 = pt;            // c = b*16+lo16 == lane
    }
    // ---- tiles 4..7: raw F (pre-packed) -> hi-dup B-frag -> agg ----
    #pragma unroll
    for (int bt = 0; bt < 4; bt++){
        FragU bfg;
        bfg.u[0] = fh01[bt]; bfg.u[1] = fh23[bt];
        bfg.u[2] = fh01[bt]; bfg.u[3] = fh23[bt];
        f32x4 da = {0.f,0.f,0.f,0.f};
        da = __builtin_amdgcn_mfma_f32_16x16x32_bf16(xA.f, bfg.f, da, 0,0,0);
        const float4 ew = *(const float4*)&sEndw[(64 + bt*16 + lo16)*20 + quad*4];
        float pt = da[0]*ew.x + da[1]*ew.y + da[2]*ew.z + da[3]*ew.w;
        pt += __shfl_xor(pt, 16, 64);
        pt += __shfl_xor(pt, 32, 64);
        if (bt == quad) o1 = pt;           // c = 64 + bt*16+lo16 == 64+lane
    }

    out[(size_t)nr*CM + lane]      = o0 + endb0;
    out[(size_t)nr*CM + 64 + lane] = o1 + endb1;
}

extern "C" void kernel_launch(void* const* d_in, const int* in_sizes, int n_in,
                              void* d_out, int out_size, void* d_ws, size_t ws_size,
                              hipStream_t stream)
{
    const float* p     = (const float*)d_in[0];
    const float* P     = (const float*)d_in[1];
    const float* F     = (const float*)d_in[2];
    const float* gamma = (const float*)d_in[3];
    const float* beta  = (const float*)d_in[4];
    const float* w1    = (const float*)d_in[5];
    const float* b1    = (const float*)d_in[6];
    const float* w2    = (const float*)d_in[7];
    const float* b2    = (const float*)d_in[8];
    const float* midw  = (const float*)d_in[9];
    const float* midb  = (const float*)d_in[10];
    const float* mlpw  = (const float*)d_in[11];
    const float* mlpb  = (const float*)d_in[12];
    const float* endw  = (const float*)d_in[13];
    const float* endb  = (const float*)d_in[14];
    float* ws  = (float*)d_ws;
    float* out = (float*)d_out;

    xconv_stats<<<256, 256, 0, stream>>>(p, P, w1, b1, w2, ws);
    xconv_bn   <<<1,    64, 0, stream>>>(ws, gamma, beta);
    xconv_main <<<4096, 256, 0, stream>>>(p, P, F, mlpw, mlpb, midw, midb,
                                          b2, endw, endb, out);
}